// Round 10
// baseline (1693.616 us; speedup 1.0000x reference)
//
#include <hip/hip_runtime.h>

#define NUM_USERS 100000
#define NUM_ITEMS 200000
#define EMB_DIM   64
#define NNODES    (NUM_USERS + NUM_ITEMS)   // 300000
#define NNZ_C     10000000
#define BATCH_C   8192

#define NBUCK     4688                      // ceil(NNODES/64)
#define NPART     8                         // partitions ~ XCDs (blockIdx&7)
#define NSEG      (NBUCK * NPART)           // 37504 segments
#define SCAT_GRID 2048                      // MUST match between hist & scatter
#define SCAN_ITEMS 37                       // ceil(NSEG/1024)

typedef unsigned long long u64;

// bucket record: col(19b) | row_low6 << 19 | val_bits << 32
// final CSR record: col (low 32) | val_bits (high 32)
__device__ __forceinline__ unsigned short f2bf(float f) {
    unsigned u = __float_as_uint(f);
    u += 0x7fffu + ((u >> 16) & 1u);
    return (unsigned short)(u >> 16);
}
__device__ __forceinline__ float bf2f(unsigned short h) {
    return __uint_as_float((unsigned)h << 16);
}

// ---------------------------------------------------------------------------
// utility zero kernels (no hipMemsetAsync — graph capture safety)
// ---------------------------------------------------------------------------
__global__ void zero_int_kernel(int* __restrict__ p, int n) {
    int i = blockIdx.x * blockDim.x + threadIdx.x;
    if (i < n) p[i] = 0;
}
__global__ void zero_f32_kernel(float* __restrict__ p, long long n) {
    long long i = (long long)blockIdx.x * blockDim.x + threadIdx.x;
    long long stride = (long long)gridDim.x * blockDim.x;
    for (; i < n; i += stride) p[i] = 0.f;
}

// ---------------------------------------------------------------------------
// convert x0 = concat(uemb, iemb) to bf16
// ---------------------------------------------------------------------------
__global__ void convert_x0_kernel(const float* __restrict__ uemb,
                                  const float* __restrict__ iemb,
                                  ushort* __restrict__ x0) {
    const long long total4 = (long long)NNODES * EMB_DIM / 4;
    const long long usr4   = (long long)NUM_USERS * EMB_DIM / 4;
    long long g = (long long)blockIdx.x * blockDim.x + threadIdx.x;
    long long stride = (long long)gridDim.x * blockDim.x;
    for (; g < total4; g += stride) {
        long long base = g * 4;
        const float* src = (g < usr4) ? (uemb + base)
                                      : (iemb + (base - (long long)NUM_USERS * EMB_DIM));
        float4 v = *reinterpret_cast<const float4*>(src);
        *reinterpret_cast<ushort4*>(x0 + base) =
            make_ushort4(f2bf(v.x), f2bf(v.y), f2bf(v.z), f2bf(v.w));
    }
}

// ---------------------------------------------------------------------------
// 1) per-(bucket,partition) edge counts. Partition = blockIdx&7 so the same
//    edge maps to the same segment in hist and scatter (identical grids).
// ---------------------------------------------------------------------------
__global__ void bucket_hist_kernel(const int* __restrict__ rows,
                                   int* __restrict__ cnt) {
    int p = blockIdx.x & (NPART - 1);
    int i = blockIdx.x * blockDim.x + threadIdx.x;
    int stride = gridDim.x * blockDim.x;
    for (; i < NNZ_C; i += stride) {
        int r = __builtin_nontemporal_load(rows + i);
        atomicAdd(&cnt[(r >> 6) * NPART + p], 1);
    }
}

// ---------------------------------------------------------------------------
// 2) exclusive scan over all NSEG counts (b-major: bucket's 8 segments are
//    contiguous, so seg_base[b*8] is also the bucket's global CSR offset).
// ---------------------------------------------------------------------------
__global__ __launch_bounds__(1024) void bucket_scan_kernel(
        const int* __restrict__ cnt, int* __restrict__ base,
        int* __restrict__ cur) {
    __shared__ int sm[1024];
    int t = threadIdx.x;
    int first = t * SCAN_ITEMS;
    int v[SCAN_ITEMS];
    int s = 0;
#pragma unroll
    for (int k = 0; k < SCAN_ITEMS; ++k) {
        int idx = first + k;
        v[k] = (idx < NSEG) ? cnt[idx] : 0;
        s += v[k];
    }
    sm[t] = s;
    __syncthreads();
    for (int off = 1; off < 1024; off <<= 1) {
        int val = (t >= off) ? sm[t - off] : 0;
        __syncthreads();
        sm[t] += val;
        __syncthreads();
    }
    int run = sm[t] - s;
#pragma unroll
    for (int k = 0; k < SCAN_ITEMS; ++k) {
        int idx = first + k;
        if (idx < NSEG) { base[idx] = run; cur[idx] = run; run += v[k]; }
    }
    if (t == 0) base[NSEG] = NNZ_C;
}

// ---------------------------------------------------------------------------
// 3) bucket scatter: edge -> tmp[cursor(bucket,partition)++]. Each segment's
//    write front is one line filled by one partition class -> assembled in a
//    single XCD L2 (if blockIdx&7 ~ XCD) -> ~1x write amplification.
// ---------------------------------------------------------------------------
__global__ void bucket_scatter_kernel(const int* __restrict__ rows,
                                      const int* __restrict__ cols,
                                      const float* __restrict__ vals,
                                      int* __restrict__ cur,
                                      u64* __restrict__ tmp) {
    int p = blockIdx.x & (NPART - 1);
    int i = blockIdx.x * blockDim.x + threadIdx.x;
    int stride = gridDim.x * blockDim.x;
    for (; i < NNZ_C; i += stride) {
        int r   = __builtin_nontemporal_load(rows + i);
        int c   = __builtin_nontemporal_load(cols + i);
        float v = __builtin_nontemporal_load(vals + i);
        int pos = atomicAdd(&cur[(r >> 6) * NPART + p], 1);
        u64 rec = (u64)((unsigned)c | ((unsigned)(r & 63) << 19)) |
                  ((u64)__float_as_uint(v) << 32);
        tmp[pos] = rec;
    }
}

// ---------------------------------------------------------------------------
// 4) finalize: per bucket (contiguous segment of tmp), count rows in LDS,
//    scan 64, emit row_ptr, then place edges at exact CSR offsets. Both the
//    reads and the writes live in the same hot ~17 KB range.
// ---------------------------------------------------------------------------
__global__ __launch_bounds__(256) void csr_finalize_kernel(
        const u64* __restrict__ tmp, const int* __restrict__ base,
        int* __restrict__ row_ptr, u64* __restrict__ ccv) {
    int b = blockIdx.x;
    int s = base[b * NPART];
    int e = base[b * NPART + NPART];
    int t = threadIdx.x;

    __shared__ int cnt[64];
    __shared__ int off[64];
    __shared__ int cur[64];

    if (t < 64) cnt[t] = 0;
    __syncthreads();
    for (int i = s + t; i < e; i += 256) {
        int rl = (int)((tmp[i] >> 19) & 63);
        atomicAdd(&cnt[rl], 1);
    }
    __syncthreads();
    if (t == 0) {
        int acc = 0;
        for (int r = 0; r < 64; ++r) { off[r] = acc; acc += cnt[r]; }
    }
    __syncthreads();
    int brow = b * 64;
    if (t < 64 && brow + t < NNODES) row_ptr[brow + t] = s + off[t];
    if (b == 0 && t == 0) row_ptr[NNODES] = NNZ_C;
    if (t < 64) cur[t] = s + off[t];
    __syncthreads();
    for (int i = s + t; i < e; i += 256) {
        u64 v = tmp[i];
        int rl = (int)((v >> 19) & 63);
        int pos = atomicAdd(&cur[rl], 1);
        ccv[pos] = (v & 0xffffffff00000000ull) | (v & 0x7ffffull);
    }
}

// ---------------------------------------------------------------------------
// 5) row-parallel gather SpMM, bf16 state (unchanged from R8)
// ---------------------------------------------------------------------------
template <bool ACCUM>
__global__ __launch_bounds__(256) void spmm_bf_kernel(
        const int* __restrict__ row_ptr, const u64* __restrict__ ccv,
        const ushort* __restrict__ xin, ushort* __restrict__ xout) {
    int row = blockIdx.x * 16 + (threadIdx.x >> 4);
    int lane = threadIdx.x & 63;
    int dl = lane & 15;
    int base = lane & 48;

    int start = row_ptr[row];
    int end   = row_ptr[row + 1];

    float ax = 0.f, ay = 0.f, az = 0.f, aw = 0.f;

    int cur = start;
    for (; cur + 16 <= end; cur += 16) {
        u64 e = __builtin_nontemporal_load(ccv + cur + dl);
        int   c = (int)(unsigned int)(e & 0xffffffffu);
        float v = __uint_as_float((unsigned int)(e >> 32));
#pragma unroll
        for (int j = 0; j < 16; ++j) {
            int   cj = __shfl(c, base + j);
            float vj = __shfl(v, base + j);
            ushort4 xb = *reinterpret_cast<const ushort4*>(
                xin + (size_t)cj * EMB_DIM + dl * 4);
            ax += vj * bf2f(xb.x);
            ay += vj * bf2f(xb.y);
            az += vj * bf2f(xb.z);
            aw += vj * bf2f(xb.w);
        }
    }
    int n = end - cur;
    if (n > 0) {
        int   c = 0;
        float v = 0.f;
        if (dl < n) {
            u64 e = ccv[cur + dl];
            c = (int)(unsigned int)(e & 0xffffffffu);
            v = __uint_as_float((unsigned int)(e >> 32));
        }
        for (int j = 0; j < n; ++j) {
            int   cj = __shfl(c, base + j);
            float vj = __shfl(v, base + j);
            ushort4 xb = *reinterpret_cast<const ushort4*>(
                xin + (size_t)cj * EMB_DIM + dl * 4);
            ax += vj * bf2f(xb.x);
            ay += vj * bf2f(xb.y);
            az += vj * bf2f(xb.z);
            aw += vj * bf2f(xb.w);
        }
    }

    ushort4* o = reinterpret_cast<ushort4*>(xout + (size_t)row * EMB_DIM) + dl;
    if (ACCUM) {
        ushort4 old = *o;
        ax += bf2f(old.x); ay += bf2f(old.y); az += bf2f(old.z); aw += bf2f(old.w);
    }
    *o = make_ushort4(f2bf(ax), f2bf(ay), f2bf(az), f2bf(aw));
}

// ---------------------------------------------------------------------------
// fallback path (small ws): COO edge-parallel atomic scatter, f32
// ---------------------------------------------------------------------------
template <bool FIRST>
__global__ __launch_bounds__(256) void coo_spmm_kernel(
        const int* __restrict__ rows, const int* __restrict__ cols,
        const float* __restrict__ vals, const float* __restrict__ xin,
        const float* __restrict__ uemb, const float* __restrict__ iemb,
        float* __restrict__ xout) {
    long long e = (long long)blockIdx.x * 16 + (threadIdx.x >> 4);
    int dl = threadIdx.x & 15;
    if (e >= NNZ_C) return;
    int r = rows[e];
    int c = cols[e];
    float v = vals[e];
    const float* src;
    if (FIRST) {
        src = (c < NUM_USERS) ? (uemb + (size_t)c * EMB_DIM)
                              : (iemb + (size_t)(c - NUM_USERS) * EMB_DIM);
    } else {
        src = xin + (size_t)c * EMB_DIM;
    }
    float4 xv = *reinterpret_cast<const float4*>(src + dl * 4);
    float* dst = xout + (size_t)r * EMB_DIM + dl * 4;
    atomicAdd(dst + 0, v * xv.x);
    atomicAdd(dst + 1, v * xv.y);
    atomicAdd(dst + 2, v * xv.z);
    atomicAdd(dst + 3, v * xv.w);
}

// ---------------------------------------------------------------------------
// readout: out[b] = dot(acc_u[u], acc_i[i]) / 16  (acc = x0 + A + B)
// ---------------------------------------------------------------------------
__global__ __launch_bounds__(256) void dot_bf_kernel(
        const float* __restrict__ uemb, const float* __restrict__ iemb,
        const ushort* __restrict__ A, const ushort* __restrict__ B,
        const int* __restrict__ u_idx, const int* __restrict__ i_idx,
        float* __restrict__ out) {
    int t = blockIdx.x * blockDim.x + threadIdx.x;
    int b = t >> 4;
    int dl = t & 15;
    if (b >= BATCH_C) return;

    int u = u_idx[b];
    int ii = i_idx[b];
    size_t uoff  = (size_t)u * EMB_DIM + dl * 4;
    size_t ioff  = (size_t)ii * EMB_DIM + dl * 4;
    size_t Aioff = (size_t)(NUM_USERS + ii) * EMB_DIM + dl * 4;

    float4 e_u = *reinterpret_cast<const float4*>(uemb + uoff);
    float4 e_i = *reinterpret_cast<const float4*>(iemb + ioff);
    ushort4 a_u = *reinterpret_cast<const ushort4*>(A + uoff);
    ushort4 b_u = *reinterpret_cast<const ushort4*>(B + uoff);
    ushort4 a_i = *reinterpret_cast<const ushort4*>(A + Aioff);
    ushort4 b_i = *reinterpret_cast<const ushort4*>(B + Aioff);

    float ux = e_u.x + bf2f(a_u.x) + bf2f(b_u.x);
    float uy = e_u.y + bf2f(a_u.y) + bf2f(b_u.y);
    float uz = e_u.z + bf2f(a_u.z) + bf2f(b_u.z);
    float uw = e_u.w + bf2f(a_u.w) + bf2f(b_u.w);
    float ix = e_i.x + bf2f(a_i.x) + bf2f(b_i.x);
    float iy = e_i.y + bf2f(a_i.y) + bf2f(b_i.y);
    float iz = e_i.z + bf2f(a_i.z) + bf2f(b_i.z);
    float iw = e_i.w + bf2f(a_i.w) + bf2f(b_i.w);

    float s = ux * ix + uy * iy + uz * iz + uw * iw;
    s += __shfl_xor(s, 1);
    s += __shfl_xor(s, 2);
    s += __shfl_xor(s, 4);
    s += __shfl_xor(s, 8);
    if (dl == 0) out[b] = s * 0.0625f;
}

__global__ __launch_bounds__(256) void dot_f32_kernel(
        const float* __restrict__ uemb, const float* __restrict__ iemb,
        const float* __restrict__ A, const float* __restrict__ B,
        const int* __restrict__ u_idx, const int* __restrict__ i_idx,
        float* __restrict__ out) {
    int t = blockIdx.x * blockDim.x + threadIdx.x;
    int b = t >> 4;
    int dl = t & 15;
    if (b >= BATCH_C) return;

    int u = u_idx[b];
    int ii = i_idx[b];
    size_t uoff  = (size_t)u * EMB_DIM + dl * 4;
    size_t ioff  = (size_t)ii * EMB_DIM + dl * 4;
    size_t Aioff = (size_t)(NUM_USERS + ii) * EMB_DIM + dl * 4;

    float4 e_u = *reinterpret_cast<const float4*>(uemb + uoff);
    float4 a_u = *reinterpret_cast<const float4*>(A + uoff);
    float4 b_u = *reinterpret_cast<const float4*>(B + uoff);
    float4 e_i = *reinterpret_cast<const float4*>(iemb + ioff);
    float4 a_i = *reinterpret_cast<const float4*>(A + Aioff);
    float4 b_i = *reinterpret_cast<const float4*>(B + Aioff);

    float ux = e_u.x + a_u.x + b_u.x, uy = e_u.y + a_u.y + b_u.y;
    float uz = e_u.z + a_u.z + b_u.z, uw = e_u.w + a_u.w + b_u.w;
    float ix = e_i.x + a_i.x + b_i.x, iy = e_i.y + a_i.y + b_i.y;
    float iz = e_i.z + a_i.z + b_i.z, iw = e_i.w + a_i.w + b_i.w;

    float s = ux * ix + uy * iy + uz * iz + uw * iw;
    s += __shfl_xor(s, 1);
    s += __shfl_xor(s, 2);
    s += __shfl_xor(s, 4);
    s += __shfl_xor(s, 8);
    if (dl == 0) out[b] = s * 0.0625f;
}

// ---------------------------------------------------------------------------
extern "C" void kernel_launch(void* const* d_in, const int* in_sizes, int n_in,
                              void* d_out, int out_size, void* d_ws, size_t ws_size,
                              hipStream_t stream) {
    const float* uemb     = (const float*)d_in[0];
    const float* iemb     = (const float*)d_in[1];
    const float* adj_vals = (const float*)d_in[2];
    const int*   adj_rows = (const int*)d_in[3];
    const int*   adj_cols = (const int*)d_in[4];
    const int*   u_idx    = (const int*)d_in[5];
    const int*   i_idx    = (const int*)d_in[6];
    float* out = (float*)d_out;
    (void)in_sizes; (void)n_in; (void)out_size;

    const size_t DENSE_BF  = (size_t)NNODES * EMB_DIM * 2;   // 38.4 MB
    const size_t DENSE_F32 = (size_t)NNODES * EMB_DIM * 4;   // 76.8 MB
    const size_t EDGES     = (size_t)NNZ_C * 8;              // 80 MB
    const size_t ALIGN = 256;
    auto rnd = [&](size_t b) { return (b + ALIGN - 1) & ~(ALIGN - 1); };

    // region0 holds tmp (CSR build) then X0|A|B (propagation) — never live together
    const size_t region0 = rnd(DENSE_BF * 3 > EDGES ? DENSE_BF * 3 : EDGES);
    const size_t need_full = region0 + rnd(EDGES) + rnd((size_t)(NNODES + 1) * 4) +
                             rnd((size_t)(NSEG + 1) * 4) * 3;          // ~197 MB
    const size_t need_min  = rnd(DENSE_F32) * 2;                        // ~154 MB

    const long long dense_elems = (long long)NNODES * EMB_DIM;
    const int dot_grid = (BATCH_C * 16 + 255) / 256;

    if (ws_size >= need_full) {
        size_t off = 0;
        auto alloc = [&](size_t bytes) -> void* {
            void* p = (char*)d_ws + off;
            off += rnd(bytes);
            return p;
        };
        char*  r0      = (char*)alloc(region0);
        u64*   ccv     = (u64*) alloc(EDGES);
        int*   row_ptr = (int*) alloc((size_t)(NNODES + 1) * 4);
        int*   bbase   = (int*) alloc((size_t)(NSEG + 1) * 4);
        int*   bcur    = (int*) alloc((size_t)(NSEG + 1) * 4);
        int*   bcnt    = (int*) alloc((size_t)(NSEG + 1) * 4);

        u64*    tmp = (u64*)r0;                 // live: CSR build only
        ushort* X0  = (ushort*)r0;              // live: after csr_finalize
        ushort* A   = X0 + dense_elems;
        ushort* B   = A + dense_elems;

        // CSR build (two-phase binned)
        zero_int_kernel<<<(NSEG + 255) / 256, 256, 0, stream>>>(bcnt, NSEG);
        bucket_hist_kernel<<<SCAT_GRID, 256, 0, stream>>>(adj_rows, bcnt);
        bucket_scan_kernel<<<1, 1024, 0, stream>>>(bcnt, bbase, bcur);
        bucket_scatter_kernel<<<SCAT_GRID, 256, 0, stream>>>(adj_rows, adj_cols,
                                                             adj_vals, bcur, tmp);
        csr_finalize_kernel<<<NBUCK, 256, 0, stream>>>(tmp, bbase, row_ptr, ccv);

        // propagation (bf16 state)
        convert_x0_kernel<<<2048, 256, 0, stream>>>(uemb, iemb, X0);
        const int spmm_grid = NNODES / 16;   // 18750
        spmm_bf_kernel<false><<<spmm_grid, 256, 0, stream>>>(row_ptr, ccv, X0, A);
        spmm_bf_kernel<false><<<spmm_grid, 256, 0, stream>>>(row_ptr, ccv, A, B);
        spmm_bf_kernel<true ><<<spmm_grid, 256, 0, stream>>>(row_ptr, ccv, B, A);

        dot_bf_kernel<<<dot_grid, 256, 0, stream>>>(uemb, iemb, A, B, u_idx, i_idx, out);
    } else if (ws_size >= need_min) {
        float* A = (float*)d_ws;
        float* B = (float*)((char*)d_ws + rnd(DENSE_F32));
        const int coo_grid = (NNZ_C + 15) / 16;

        zero_f32_kernel<<<2048, 256, 0, stream>>>(A, dense_elems);
        coo_spmm_kernel<true ><<<coo_grid, 256, 0, stream>>>(adj_rows, adj_cols, adj_vals,
                                                             nullptr, uemb, iemb, A);
        zero_f32_kernel<<<2048, 256, 0, stream>>>(B, dense_elems);
        coo_spmm_kernel<false><<<coo_grid, 256, 0, stream>>>(adj_rows, adj_cols, adj_vals,
                                                             A, nullptr, nullptr, B);
        coo_spmm_kernel<false><<<coo_grid, 256, 0, stream>>>(adj_rows, adj_cols, adj_vals,
                                                             B, nullptr, nullptr, A);

        dot_f32_kernel<<<dot_grid, 256, 0, stream>>>(uemb, iemb, A, B, u_idx, i_idx, out);
    }
    // else: insufficient workspace — launch nothing (diagnostic mismatch, no crash)
}